// Round 1
// 570.995 us; speedup vs baseline: 1.0833x; 1.0833x over previous
//
#include <hip/hip_runtime.h>
#include <stdint.h>

#define L_TOK 16384
#define DM 256
#define DI 512
#define DS 64
#define NH 8
#define HD 64
#define CD 640
#define DP 1160
#define CHUNK 64
#define NC 256
#define EPSF 1e-5f

typedef __attribute__((ext_vector_type(8))) short short8;
typedef __attribute__((ext_vector_type(4))) float f32x4;

#define GLL16(gp, lp) __builtin_amdgcn_global_load_lds((const __attribute__((address_space(1))) void*)(gp), (__attribute__((address_space(3))) void*)(lp), 16, 0, 0)

__device__ __forceinline__ float warp_sum(float v) {
  v += __shfl_xor(v, 1, 64);
  v += __shfl_xor(v, 2, 64);
  v += __shfl_xor(v, 4, 64);
  v += __shfl_xor(v, 8, 64);
  v += __shfl_xor(v, 16, 64);
  v += __shfl_xor(v, 32, 64);
  return v;
}

__device__ __forceinline__ float siluf(float x) { return x / (1.0f + expf(-x)); }

__device__ __forceinline__ unsigned short f2bf(float f) {
  unsigned int u = __float_as_uint(f);
  unsigned int r = (u + 0x7FFFu + ((u >> 16) & 1u)) >> 16;
  return (unsigned short)r;
}
__device__ __forceinline__ float bf2f(unsigned short u) {
  return __uint_as_float(((unsigned int)u) << 16);
}

// ---------------- serialization ----------------

__global__ __launch_bounds__(256) void minmax_kernel(const float* __restrict__ pos, float* __restrict__ pmm) {
  __shared__ float sm[6][256];
  int tid = threadIdx.x;
  float mn0=1e30f, mn1=1e30f, mn2=1e30f, mx0=-1e30f, mx1=-1e30f, mx2=-1e30f;
  for (int t = tid; t < L_TOK; t += 256) {
    float a = pos[t*3+0], b = pos[t*3+1], c = pos[t*3+2];
    mn0=fminf(mn0,a); mx0=fmaxf(mx0,a);
    mn1=fminf(mn1,b); mx1=fmaxf(mx1,b);
    mn2=fminf(mn2,c); mx2=fmaxf(mx2,c);
  }
  sm[0][tid]=mn0; sm[1][tid]=mn1; sm[2][tid]=mn2;
  sm[3][tid]=mx0; sm[4][tid]=mx1; sm[5][tid]=mx2;
  __syncthreads();
  for (int s = 128; s > 0; s >>= 1) {
    if (tid < s) {
      #pragma unroll
      for (int d = 0; d < 3; ++d) {
        sm[d][tid]   = fminf(sm[d][tid],   sm[d][tid+s]);
        sm[3+d][tid] = fmaxf(sm[3+d][tid], sm[3+d][tid+s]);
      }
    }
    __syncthreads();
  }
  if (tid < 6) pmm[tid] = sm[tid][0];
}

__device__ unsigned int hilbert3(unsigned int a, unsigned int b, unsigned int c) {
  unsigned int x0 = a, x1 = b, x2 = c;
  for (unsigned int Q = 512u; Q > 1u; Q >>= 1) {
    unsigned int P = Q - 1u;
    { if (x0 & Q) x0 ^= P; }
    {
      unsigned int t = (x0 ^ x1) & P;
      if (x1 & Q) { x0 ^= P; }
      else { x0 ^= t; x1 ^= t; }
    }
    {
      unsigned int t = (x0 ^ x2) & P;
      if (x2 & Q) { x0 ^= P; }
      else { x0 ^= t; x2 ^= t; }
    }
  }
  x1 ^= x0; x2 ^= x1;
  unsigned int tt = 0;
  for (unsigned int Q = 512u; Q > 1u; Q >>= 1)
    if (x2 & Q) tt ^= (Q - 1u);
  x0 ^= tt; x1 ^= tt; x2 ^= tt;
  unsigned int code = 0;
  #pragma unroll
  for (int bb = 9; bb >= 0; --bb) {
    code = (code << 1) | ((x0 >> bb) & 1u);
    code = (code << 1) | ((x1 >> bb) & 1u);
    code = (code << 1) | ((x2 >> bb) & 1u);
  }
  return code;
}

__global__ __launch_bounds__(256) void hilbert_kernel(const float* __restrict__ pos, const float* __restrict__ pmm,
                                                      unsigned long long* __restrict__ keys) {
  int t = blockIdx.x*256 + threadIdx.x;
  if (t >= L_TOK) return;
  unsigned int g[3];
  #pragma unroll
  for (int d = 0; d < 3; ++d) {
    float v = (pos[t*3+d] - pmm[d]) / (pmm[3+d] - pmm[d] + 1e-6f) * 1023.0f;
    v = fminf(fmaxf(v, 0.0f), 1023.0f);
    g[d] = (unsigned int)(int)v;
  }
  unsigned int ca = hilbert3(g[0], g[1], g[2]);
  unsigned int cb = hilbert3(g[1], g[0], g[2]);
  keys[t]         = ((unsigned long long)ca << 14) | (unsigned long long)t;
  keys[L_TOK + t] = ((unsigned long long)cb << 14) | (unsigned long long)t;
}

__global__ __launch_bounds__(256) void rank_partial(const unsigned long long* __restrict__ keys,
                                                    unsigned int* __restrict__ partial) {
  __shared__ unsigned long long tile[512];
  int arr = blockIdx.y, ks = blockIdx.z;
  const unsigned long long* k = keys + (size_t)arr * L_TOK;
  int qbase = blockIdx.x*1024 + threadIdx.x;
  unsigned long long q[4];
  #pragma unroll
  for (int i = 0; i < 4; ++i) q[i] = k[qbase + 256*i];
  const unsigned long long* src = k + ks*512;
  #pragma unroll
  for (int t = 0; t < 2; ++t) tile[threadIdx.x + 256*t] = src[threadIdx.x + 256*t];
  __syncthreads();
  unsigned int r[4] = {};
  const ulonglong2* t2 = (const ulonglong2*)tile;
  #pragma unroll 4
  for (int j = 0; j < 256; ++j) {
    ulonglong2 v = t2[j];
    #pragma unroll
    for (int i = 0; i < 4; ++i) {
      r[i] += (v.x < q[i]) ? 1u : 0u;
      r[i] += (v.y < q[i]) ? 1u : 0u;
    }
  }
  #pragma unroll
  for (int i = 0; i < 4; ++i)
    partial[(size_t)(ks*2 + arr)*L_TOK + qbase + 256*i] = r[i];
}

__global__ __launch_bounds__(256) void rank_scatter(const unsigned long long* __restrict__ keys,
                                                    const unsigned int* __restrict__ partial,
                                                    unsigned int* __restrict__ ord,
                                                    unsigned int* __restrict__ inv) {
  int i = blockIdx.x*256 + threadIdx.x;
  int arr = i >> 14;
  int qi = i & (L_TOK - 1);
  unsigned int r = 0;
  #pragma unroll
  for (int ks = 0; ks < 32; ++ks) r += partial[(size_t)(ks*2 + arr)*L_TOK + qi];
  unsigned int tok = (unsigned int)(keys[i] & 0x3FFFu);
  ord[(size_t)arr*L_TOK + r] = tok;
  inv[(size_t)arr*L_TOK + tok] = r;
}

// ---------------- layernorm / gating ----------------

__global__ __launch_bounds__(256) void ln_kernel(const float* __restrict__ in, float* __restrict__ out,
                                                 unsigned short* __restrict__ outbf,
                                                 const float* __restrict__ w, const float* __restrict__ b) {
  int row = blockIdx.x*4 + (threadIdx.x >> 6);
  int lane = threadIdx.x & 63;
  const float4 v = *(const float4*)(in + (size_t)row*DM + lane*4);
  float s = v.x + v.y + v.z + v.w;
  float mean = warp_sum(s) * (1.0f/DM);
  float4 xc = make_float4(v.x-mean, v.y-mean, v.z-mean, v.w-mean);
  float ss = xc.x*xc.x + xc.y*xc.y + xc.z*xc.z + xc.w*xc.w;
  ss = warp_sum(ss) * (1.0f/DM);
  float inv = rsqrtf(ss + EPSF);
  const float4 w4 = *(const float4*)(w + lane*4);
  const float4 b4 = *(const float4*)(b + lane*4);
  float4 o;
  o.x = xc.x*inv*w4.x + b4.x;
  o.y = xc.y*inv*w4.y + b4.y;
  o.z = xc.z*inv*w4.z + b4.z;
  o.w = xc.w*inv*w4.w + b4.w;
  *(float4*)(out + (size_t)row*DM + lane*4) = o;
  if (outbf) {
    ushort4 ob = make_ushort4(f2bf(o.x), f2bf(o.y), f2bf(o.z), f2bf(o.w));
    *(ushort4*)(outbf + (size_t)row*DM + lane*4) = ob;
  }
}

// fin-LN (in place on io) fused with next layer's pre-LN (writes qn/qnbf) in one read
__global__ __launch_bounds__(256) void lnfuse_kernel(float* __restrict__ io,
                                                     float* __restrict__ qn, unsigned short* __restrict__ qnbf,
                                                     const float* __restrict__ fw, const float* __restrict__ fb,
                                                     const float* __restrict__ pw, const float* __restrict__ pb) {
  int row = blockIdx.x*4 + (threadIdx.x >> 6);
  int lane = threadIdx.x & 63;
  const float4 v = *(const float4*)(io + (size_t)row*DM + lane*4);
  float s = v.x + v.y + v.z + v.w;
  float mean = warp_sum(s) * (1.0f/DM);
  float4 xc = make_float4(v.x-mean, v.y-mean, v.z-mean, v.w-mean);
  float ss = xc.x*xc.x + xc.y*xc.y + xc.z*xc.z + xc.w*xc.w;
  ss = warp_sum(ss) * (1.0f/DM);
  float inv = rsqrtf(ss + EPSF);
  const float4 w4 = *(const float4*)(fw + lane*4);
  const float4 b4 = *(const float4*)(fb + lane*4);
  float4 o;
  o.x = xc.x*inv*w4.x + b4.x;
  o.y = xc.y*inv*w4.y + b4.y;
  o.z = xc.z*inv*w4.z + b4.z;
  o.w = xc.w*inv*w4.w + b4.w;
  *(float4*)(io + (size_t)row*DM + lane*4) = o;
  if (qn) {
    float s2 = o.x + o.y + o.z + o.w;
    float mean2 = warp_sum(s2) * (1.0f/DM);
    float4 x2 = make_float4(o.x-mean2, o.y-mean2, o.z-mean2, o.w-mean2);
    float ss2 = x2.x*x2.x + x2.y*x2.y + x2.z*x2.z + x2.w*x2.w;
    ss2 = warp_sum(ss2) * (1.0f/DM);
    float inv2 = rsqrtf(ss2 + EPSF);
    const float4 pw4 = *(const float4*)(pw + lane*4);
    const float4 pb4 = *(const float4*)(pb + lane*4);
    float4 qv;
    qv.x = x2.x*inv2*pw4.x + pb4.x;
    qv.y = x2.y*inv2*pw4.y + pb4.y;
    qv.z = x2.z*inv2*pw4.z + pb4.z;
    qv.w = x2.w*inv2*pw4.w + pb4.w;
    *(float4*)(qn + (size_t)row*DM + lane*4) = qv;
    ushort4 qb = make_ushort4(f2bf(qv.x), f2bf(qv.y), f2bf(qv.z), f2bf(qv.w));
    *(ushort4*)(qnbf + (size_t)row*DM + lane*4) = qb;
  }
}

__global__ __launch_bounds__(256) void gating_kernel(unsigned short* __restrict__ ybase,
                                                     const unsigned short* __restrict__ gatebf,
                                                     const float* __restrict__ nw) {
  int row = blockIdx.x*4 + (threadIdx.x >> 6);
  int lane = threadIdx.x & 63;
  int dir = row >> 14, lrow = row & (L_TOK - 1);
  unsigned short* yr = ybase + (size_t)dir*L_TOK*CD + (size_t)lrow*DI;
  const unsigned short* gr = gatebf + (size_t)dir*L_TOK*DI + (size_t)lrow*DI;
  ushort4 yu0 = *(const ushort4*)(yr + lane*4);
  ushort4 yu1 = *(const ushort4*)(yr + 256 + lane*4);
  ushort4 gu0 = *(const ushort4*)(gr + lane*4);
  ushort4 gu1 = *(const ushort4*)(gr + 256 + lane*4);
  float4 y0 = make_float4(bf2f(yu0.x), bf2f(yu0.y), bf2f(yu0.z), bf2f(yu0.w));
  float4 y1 = make_float4(bf2f(yu1.x), bf2f(yu1.y), bf2f(yu1.z), bf2f(yu1.w));
  y0.x *= siluf(bf2f(gu0.x)); y0.y *= siluf(bf2f(gu0.y)); y0.z *= siluf(bf2f(gu0.z)); y0.w *= siluf(bf2f(gu0.w));
  y1.x *= siluf(bf2f(gu1.x)); y1.y *= siluf(bf2f(gu1.y)); y1.z *= siluf(bf2f(gu1.z)); y1.w *= siluf(bf2f(gu1.w));
  float ss = y0.x*y0.x + y0.y*y0.y + y0.z*y0.z + y0.w*y0.w
           + y1.x*y1.x + y1.y*y1.y + y1.z*y1.z + y1.w*y1.w;
  ss = warp_sum(ss) * (1.0f/DI);
  float inv = rsqrtf(ss + EPSF);
  const float4 w0 = *(const float4*)(nw + lane*4);
  const float4 w1 = *(const float4*)(nw + 256 + lane*4);
  y0.x *= inv*w0.x; y0.y *= inv*w0.y; y0.z *= inv*w0.z; y0.w *= inv*w0.w;
  y1.x *= inv*w1.x; y1.y *= inv*w1.y; y1.z *= inv*w1.z; y1.w *= inv*w1.w;
  *(ushort4*)(yr + lane*4)       = make_ushort4(f2bf(y0.x), f2bf(y0.y), f2bf(y0.z), f2bf(y0.w));
  *(ushort4*)(yr + 256 + lane*4) = make_ushort4(f2bf(y1.x), f2bf(y1.y), f2bf(y1.z), f2bf(y1.w));
}

// ---------------- weight transpose+convert ----------------

__global__ __launch_bounds__(256) void tcvt_both(const float* __restrict__ Wi, const float* __restrict__ Wo,
                                                 unsigned short* __restrict__ WtA, unsigned short* __restrict__ WtO) {
  int idx = blockIdx.x*256 + threadIdx.x;
  if (idx < 1152*DM) {
    int n = idx >> 8, k = idx & 255;
    WtA[idx] = f2bf(Wi[(size_t)k*DP + n]);
  } else {
    int j = idx - 1152*DM;
    int n = j >> 9, k = j & 511;
    WtO[j] = f2bf(Wo[(size_t)k*DM + n]);
  }
}

// ---------------- MFMA GEMMs ----------------

__global__ __launch_bounds__(256) void gemm_in_mfma(const unsigned short* __restrict__ Abf,
                                                    const unsigned short* __restrict__ Wt,
                                                    const unsigned int* __restrict__ ord,
                                                    unsigned short* __restrict__ gatebf,
                                                    unsigned short* __restrict__ xbcbf) {
  __shared__ unsigned short Alds[128*64];
  __shared__ unsigned short Blds[128*64];
  int tid = threadIdx.x, lane = tid & 63, w = tid >> 6;
  int bid = blockIdx.x;
  int xcd = bid & 7, g = bid >> 3;
  int rb = (xcd*16 + g/9)*128;
  int cb = (g % 9)*128;
  int dir = blockIdx.z;
  const unsigned int* ordp = ord + (size_t)dir*L_TOK;
  int wm = (w & 1)*64, wn = (w >> 1)*64;
  const unsigned short* pA[4]; const unsigned short* pB[4];
  unsigned short* dA[4]; unsigned short* dB[4];
  #pragma unroll
  for (int s = 0; s < 4; ++s) {
    int inst = w*4 + s;
    int r = inst*8 + (lane >> 3);
    int cA = (lane & 7) ^ (r & 7);
    pA[s] = Abf + (size_t)ordp[rb + r]*DM + cA*8;
    pB[s] = Wt + (size_t)(cb + r)*DM + cA*8;
    dA[s] = &Alds[inst*512];
    dB[s] = &Blds[inst*512];
  }
  f32x4 zero = {0.f, 0.f, 0.f, 0.f};
  f32x4 acc[4][4];
  #pragma unroll
  for (int i = 0; i < 4; ++i)
    #pragma unroll
    for (int j = 0; j < 4; ++j) acc[i][j] = zero;
  int t = lane & 15, q = lane >> 4;
  for (int k0 = 0; k0 < DM; k0 += 64) {
    #pragma unroll
    for (int s = 0; s < 4; ++s) GLL16(pA[s] + k0, dA[s]);
    #pragma unroll
    for (int s = 0; s < 4; ++s) GLL16(pB[s] + k0, dB[s]);
    __syncthreads();
    #pragma unroll
    for (int ks = 0; ks < 2; ++ks) {
      short8 af[4], bfr[4];
      int cc = ks*4 + q;
      #pragma unroll
      for (int i = 0; i < 4; ++i) {
        int rr = wm + 16*i + t;
        af[i] = *(const short8*)&Alds[rr*64 + ((cc ^ (rr & 7))*8)];
      }
      #pragma unroll
      for (int j = 0; j < 4; ++j) {
        int rr = wn + 16*j + t;
        bfr[j] = *(const short8*)&Blds[rr*64 + ((cc ^ (rr & 7))*8)];
      }
      #pragma unroll
      for (int i = 0; i < 4; ++i)
        #pragma unroll
        for (int j = 0; j < 4; ++j)
          acc[i][j] = __builtin_amdgcn_mfma_f32_16x16x32_bf16(af[i], bfr[j], acc[i][j], 0, 0, 0);
    }
    __syncthreads();
  }
  unsigned short* dst; int ld;
  if (cb < DI) { dst = gatebf + (size_t)dir*L_TOK*DI + cb; ld = DI; }
  else         { dst = xbcbf + (size_t)dir*L_TOK*CD + (cb - DI); ld = CD; }
  #pragma unroll
  for (int i = 0; i < 4; ++i) {
    int rowb = rb + wm + 16*i + q*4;
    #pragma unroll
    for (int j = 0; j < 4; ++j) {
      int col = wn + 16*j + t;
      #pragma unroll
      for (int r = 0; r < 4; ++r)
        dst[(size_t)(rowb + r)*ld + col] = f2bf(acc[i][j][r]);
    }
  }
}

// gather-based out GEMM: one launch, both dirs, natural-order output rows,
// shared B tile per K-step, no read-modify-write on out.
// out[tok] = shortcut[tok] + 0.5*(Y0[inv0[tok]] + Y1[inv1[tok]]) @ Wo
__global__ __launch_bounds__(256) void gemm_out_gather(const unsigned short* __restrict__ ybase,
                                                       const unsigned short* __restrict__ Wt,
                                                       const unsigned int* __restrict__ inv,
                                                       const float* __restrict__ shortcut,
                                                       float* __restrict__ out) {
  __shared__ unsigned short Alds[2*64*64];   // [dir][64 rows][64 k]
  __shared__ unsigned short Blds[128*64];
  int tid = threadIdx.x, lane = tid & 63, w = tid >> 6;
  int bid = blockIdx.x;
  // XCD swizzle: both col-tiles of a row-tile on the same XCD (shared gathered A rows)
  int xcd = bid & 7, g = bid >> 3;
  int rb = (xcd*32 + (g >> 1))*64;
  int cb = (g & 1)*128;
  int wm = (w & 1)*32, wn = (w >> 1)*64;
  const unsigned short* pA0[2]; const unsigned short* pA1[2];
  unsigned short* dA0[2]; unsigned short* dA1[2];
  const unsigned short* pB[4]; unsigned short* dB[4];
  #pragma unroll
  for (int s = 0; s < 2; ++s) {
    int inst = w*2 + s;
    int r = inst*8 + (lane >> 3);
    int cA = (lane & 7) ^ (r & 7);
    int tok = rb + r;
    pA0[s] = ybase + (size_t)inv[tok]*DI + cA*8;
    pA1[s] = ybase + (size_t)L_TOK*CD + (size_t)inv[L_TOK + tok]*DI + cA*8;
    dA0[s] = &Alds[inst*512];
    dA1[s] = &Alds[4096 + inst*512];
  }
  #pragma unroll
  for (int s = 0; s < 4; ++s) {
    int inst = w*4 + s;
    int r = inst*8 + (lane >> 3);
    int cA = (lane & 7) ^ (r & 7);
    pB[s] = Wt + (size_t)(cb + r)*DI + cA*8;
    dB[s] = &Blds[inst*512];
  }
  f32x4 zero = {0.f, 0.f, 0.f, 0.f};
  f32x4 acc[2][4];
  #pragma unroll
  for (int i = 0; i < 2; ++i)
    #pragma unroll
    for (int j = 0; j < 4; ++j) acc[i][j] = zero;
  int t = lane & 15, q = lane >> 4;
  for (int k0 = 0; k0 < DI; k0 += 64) {
    #pragma unroll
    for (int s = 0; s < 2; ++s) { GLL16(pA0[s] + k0, dA0[s]); GLL16(pA1[s] + k0, dA1[s]); }
    #pragma unroll
    for (int s = 0; s < 4; ++s) GLL16(pB[s] + k0, dB[s]);
    __syncthreads();
    #pragma unroll
    for (int ks = 0; ks < 2; ++ks) {
      short8 af0[2], af1[2], bfr[4];
      int cc = ks*4 + q;
      #pragma unroll
      for (int i = 0; i < 2; ++i) {
        int rr = wm + 16*i + t;
        int off = rr*64 + ((cc ^ (rr & 7))*8);
        af0[i] = *(const short8*)&Alds[off];
        af1[i] = *(const short8*)&Alds[4096 + off];
      }
      #pragma unroll
      for (int j = 0; j < 4; ++j) {
        int rr = wn + 16*j + t;
        bfr[j] = *(const short8*)&Blds[rr*64 + ((cc ^ (rr & 7))*8)];
      }
      #pragma unroll
      for (int i = 0; i < 2; ++i)
        #pragma unroll
        for (int j = 0; j < 4; ++j) {
          acc[i][j] = __builtin_amdgcn_mfma_f32_16x16x32_bf16(af0[i], bfr[j], acc[i][j], 0, 0, 0);
          acc[i][j] = __builtin_amdgcn_mfma_f32_16x16x32_bf16(af1[i], bfr[j], acc[i][j], 0, 0, 0);
        }
    }
    __syncthreads();
  }
  #pragma unroll
  for (int i = 0; i < 2; ++i) {
    #pragma unroll
    for (int r = 0; r < 4; ++r) {
      int row = rb + wm + 16*i + q*4 + r;
      const float* sp = shortcut + (size_t)row*DM + cb;
      float* op = out + (size_t)row*DM + cb;
      #pragma unroll
      for (int j = 0; j < 4; ++j) {
        int col = wn + 16*j + t;
        op[col] = sp[col] + 0.5f*acc[i][j][r];
      }
    }
  }
}

// ---------------- dt path: 8 rows/wave, LDS weights, fp32, fused softplus ----------------

__global__ __launch_bounds__(256) void dt_gemv(const float* __restrict__ qn, const float* __restrict__ W,
                                               const unsigned int* __restrict__ ord,
                                               const float* __restrict__ dt_bias, float* __restrict__ dtb) {
  __shared__ float Wl[2080];
  int tid = threadIdx.x;
  {
    const float* wp = W + (size_t)tid*DP + (DI + CD);
    float4 wa = *(const float4*)wp;
    float4 wb = *(const float4*)(wp + 4);
    int off = tid*8 + (tid >> 5)*4;
    *(float4*)&Wl[off]     = wa;
    *(float4*)&Wl[off + 4] = wb;
  }
  __syncthreads();
  int lane = tid & 63, w = tid >> 6;
  int r = blockIdx.x*32 + w*8 + (lane >> 3);
  int kg = lane & 7;
  int dir = r >> 14, lrow = r & (L_TOK - 1);
  unsigned int src = ord[(size_t)dir*L_TOK + lrow];
  const float* qp = qn + (size_t)src*DM + kg*32;
  float acc[8] = {};
  #pragma unroll
  for (int i = 0; i < 8; ++i) {
    float4 q4 = *(const float4*)(qp + i*4);
    float qv[4] = {q4.x, q4.y, q4.z, q4.w};
    #pragma unroll
    for (int e = 0; e < 4; ++e) {
      int k = kg*32 + i*4 + e;
      int off = k*8 + kg*4;
      float4 wa = *(const float4*)&Wl[off];
      float4 wb = *(const float4*)&Wl[off + 4];
      acc[0] = fmaf(qv[e], wa.x, acc[0]);
      acc[1] = fmaf(qv[e], wa.y, acc[1]);
      acc[2] = fmaf(qv[e], wa.z, acc[2]);
      acc[3] = fmaf(qv[e], wa.w, acc[3]);
      acc[4] = fmaf(qv[e], wb.x, acc[4]);
      acc[5] = fmaf(qv[e], wb.y, acc[5]);
      acc[6] = fmaf(qv[e], wb.z, acc[6]);
      acc[7] = fmaf(qv[e], wb.w, acc[7]);
    }
  }
  #pragma unroll
  for (int h = 0; h < 8; ++h) {
    acc[h] += __shfl_xor(acc[h], 8, 64);
    acc[h] += __shfl_xor(acc[h], 16, 64);
    acc[h] += __shfl_xor(acc[h], 32, 64);
  }
  float v = 0.f;
  #pragma unroll
  for (int h = 0; h < 8; ++h) if (kg == h) v = acc[h];
  v += dt_bias[kg];
  float sp = (v > 0.0f) ? (v + log1pf(expf(-v))) : log1pf(expf(v));
  dtb[(size_t)r*NH + kg] = sp;
}

// ---------------- conv: LDS-tiled, 128 tokens x 64 ch per block ----------------

__global__ __launch_bounds__(256) void conv_kernel(const unsigned short* __restrict__ xbc, const float* __restrict__ cw,
                                                   const float* __restrict__ cbias, unsigned short* __restrict__ outc) {
  __shared__ unsigned short tile[131*64];
  int tid = threadIdx.x;
  int ch0 = blockIdx.x*64;
  int t0  = blockIdx.y*128;
  int dir = blockIdx.z;
  const unsigned short* src = xbc + (size_t)dir*L_TOK*CD;
  unsigned short* dst = outc + (size_t)dir*L_TOK*CD;
  for (int c = tid; c < 131*8; c += 256) {
    int r = c >> 3, cgc = c & 7;
    int t = t0 - 3 + r;
    short8 v = {0,0,0,0,0,0,0,0};
    if (t >= 0) v = *(const short8*)(src + (size_t)t*CD + ch0 + cgc*8);
    *(short8*)&tile[r*64 + ((cgc ^ (r & 7))*8)] = v;
  }
  int cg = tid & 7, tp = tid >> 3;
  int ch = ch0 + cg*8;
  float wv[8][4];
  float bias[8];
  #pragma unroll
  for (int e = 0; e < 8; ++e) {
    float4 c4 = *(const float4*)(cw + (ch + e)*4);
    wv[e][0] = c4.x; wv[e][1] = c4.y; wv[e][2] = c4.z; wv[e][3] = c4.w;
  }
  {
    float4 b0 = *(const float4*)(cbias + ch);
    float4 b1 = *(const float4*)(cbias + ch + 4);
    bias[0]=b0.x; bias[1]=b0.y; bias[2]=b0.z; bias[3]=b0.w;
    bias[4]=b1.x; bias[5]=b1.y; bias[6]=b1.z; bias[7]=b1.w;
  }
  __syncthreads();
  #pragma unroll
  for (int tk = 0; tk < 4; ++tk) {
    int rel = tp + 32*tk;
    float acc[8];
    #pragma unroll
    for (int e = 0; e < 8; ++e) acc[e] = bias[e];
    #pragma unroll
    for (int k = 0; k < 4; ++k) {
      int r = rel + k;
      short8 v = *(const short8*)&tile[r*64 + ((cg ^ (r & 7))*8)];
      #pragma unroll
      for (int e = 0; e < 8; ++e)
        acc[e] = fmaf(wv[e][k], bf2f((unsigned short)v[e]), acc[e]);
    }
    short8 o;
    #pragma unroll
    for (int e = 0; e < 8; ++e) o[e] = (short)f2bf(siluf(acc[e]));
    *(short8*)(dst + (size_t)(t0 + rel)*CD + ch) = o;
  }
}

// ---------------- chunked scan (MFMA, bf16 S); dirs merged via blockIdx.z ----------------

__global__ __launch_bounds__(256) void phaseA_mfma(const unsigned short* __restrict__ convo,
                                                   const float* __restrict__ dtb, const float* __restrict__ A_log,
                                                   unsigned short* __restrict__ S, float* __restrict__ P) {
  int c = blockIdx.x, h = blockIdx.y, dir = blockIdx.z, tid = threadIdx.x;
  int lane = tid & 63, w = tid >> 6;
  int hh = dir*NH + h;
  const unsigned short* xc = convo + (size_t)dir*L_TOK*CD;
  __shared__ unsigned short xT[64*64];
  __shared__ unsigned short Bt[64*64];
  __shared__ float wgt[64];
  int c0 = c*CHUNK;
  float Ah = -expf(A_log[h]);
  #pragma unroll
  for (int i = 0; i < 2; ++i) {
    int q = tid + 256*i;
    int t = q >> 3, s0 = (q & 7)*8;
    short8 v = *(const short8*)(xc + (size_t)(c0+t)*CD + DI + s0);
    int tc = t >> 3, ti = t & 7;
    #pragma unroll
    for (int e = 0; e < 8; ++e) {
      int s = s0 + e;
      Bt[s*64 + ((tc ^ (s & 7))*8 + ti)] = (unsigned short)v[e];
    }
  }
  // wave0: parallel suffix scan of lg = dt*A (replaces tid==0 serial 64-iter loop)
  if (tid < 64) {
    float dtv = dtb[(size_t)(dir*L_TOK + c0 + tid)*NH + h];
    float v = dtv*Ah;
    float s = v;
    #pragma unroll
    for (int d = 1; d < 64; d <<= 1) {
      float u = __shfl_down(s, d, 64);
      s += (tid + d < 64) ? u : 0.f;
    }
    // s = inclusive suffix sum; exclusive suffix = s - v; total at lane 0
    wgt[tid] = dtv*expf(s - v);
    if (tid == 0) P[hh*NC + c] = expf(s);
  }
  __syncthreads();
  #pragma unroll
  for (int i = 0; i < 2; ++i) {
    int q = tid + 256*i;
    int t = q >> 3, p0 = (q & 7)*8;
    short8 v = *(const short8*)(xc + (size_t)(c0+t)*CD + h*HD + p0);
    float wvv = wgt[t];
    int tc = t >> 3, ti = t & 7;
    #pragma unroll
    for (int e = 0; e < 8; ++e) {
      int p = p0 + e;
      xT[p*64 + ((tc ^ (p & 7))*8 + ti)] = f2bf(bf2f((unsigned short)v[e]) * wvv);
    }
  }
  __syncthreads();
  int t16 = lane & 15, q4 = lane >> 4;
  f32x4 zero = {0.f,0.f,0.f,0.f};
  f32x4 acc[4];
  #pragma unroll
  for (int j = 0; j < 4; ++j) acc[j] = zero;
  #pragma unroll
  for (int ks = 0; ks < 2; ++ks) {
    int rowA = 16*w + t16;
    short8 a = *(const short8*)&xT[rowA*64 + (((ks*4 + q4) ^ (rowA & 7))*8)];
    #pragma unroll
    for (int j = 0; j < 4; ++j) {
      int rowB = 16*j + t16;
      short8 b = *(const short8*)&Bt[rowB*64 + (((ks*4 + q4) ^ (rowB & 7))*8)];
      acc[j] = __builtin_amdgcn_mfma_f32_16x16x32_bf16(a, b, acc[j], 0, 0, 0);
    }
  }
  unsigned short* Sp = S + ((size_t)(hh*NC + c))*4096;
  #pragma unroll
  for (int j = 0; j < 4; ++j)
    #pragma unroll
    for (int r = 0; r < 4; ++r)
      Sp[(size_t)(16*w + q4*4 + r)*64 + 16*j + t16] = f2bf(acc[j][r]);
}

// ---- phaseB: hh spans 16 (2 dirs x 8 heads) ----

__global__ __launch_bounds__(256) void phaseB1(const unsigned short* __restrict__ S, const float* __restrict__ P,
                                               float* __restrict__ Ssum, float* __restrict__ Psum) {
  int gid = blockIdx.x*256 + threadIdx.x;
  int e2 = gid & 2047;
  int sc = (gid >> 11) & 15;
  int hh = gid >> 15;
  const unsigned short* base = S + ((size_t)(hh*NC + sc*16))*4096 + e2*2;
  const float* Ph = P + hh*NC + sc*16;
  float hx = 0.f, hy = 0.f, pprod = 1.f;
  #pragma unroll
  for (int k = 0; k < 16; ++k) {
    unsigned int v = *(const unsigned int*)(base + (size_t)k*4096);
    float p = Ph[k];
    hx = p*hx + bf2f((unsigned short)(v & 0xffffu));
    hy = p*hy + bf2f((unsigned short)(v >> 16));
    pprod *= p;
  }
  float* sp = Ssum + ((size_t)(hh*16 + sc))*4096 + e2*2;
  sp[0] = hx; sp[1] = hy;
  if (e2 == 0) Psum[hh*16 + sc] = pprod;
}

__global__ __launch_bounds__(256) void phaseB3(unsigned short* __restrict__ S, const float* __restrict__ P,
                                               const float* __restrict__ Ssum, const float* __restrict__ Psum) {
  int gid = blockIdx.x*256 + threadIdx.x;
  int e2 = gid & 2047;
  int sc = (gid >> 11) & 15;
  int hh = gid >> 15;
  float hx = 0.f, hy = 0.f;
  for (int s2 = 0; s2 < sc; ++s2) {
    float pp = Psum[hh*16 + s2];
    const float* sp = Ssum + ((size_t)(hh*16 + s2))*4096 + e2*2;
    hx = pp*hx + sp[0];
    hy = pp*hy + sp[1];
  }
  unsigned short* base = S + ((size_t)(hh*NC + sc*16))*4096 + e2*2;
  const float* Ph = P + hh*NC + sc*16;
  #pragma unroll
  for (int k = 0; k < 16; ++k) {
    unsigned int* ptr = (unsigned int*)(base + (size_t)k*4096);
    unsigned int v = *ptr;
    float p = Ph[k];
    *ptr = (unsigned int)f2bf(hx) | ((unsigned int)f2bf(hy) << 16);
    hx = p*hx + bf2f((unsigned short)(v & 0xffffu));
    hy = p*hy + bf2f((unsigned short)(v >> 16));
  }
}

// phaseC: dirs merged; Y written into xbc buffer region (stride DI)
__global__ __launch_bounds__(256) void phaseC_mfma(const unsigned short* __restrict__ convo,
                                                   const float* __restrict__ dtb, const float* __restrict__ A_log,
                                                   const float* __restrict__ Dp,
                                                   const unsigned short* __restrict__ S,
                                                   unsigned short* __restrict__ ybase) {
  int c = blockIdx.x, h = blockIdx.y, dir = blockIdx.z, tid = threadIdx.x;
  int lane = tid & 63, w = tid >> 6;
  int hh = dir*NH + h;
  const unsigned short* xc = convo + (size_t)dir*L_TOK*CD;
  unsigned short* y = ybase + (size_t)dir*L_TOK*CD;
  __shared__ unsigned short Cl[64*64];
  __shared__ unsigned short Bl[64*64];
  __shared__ unsigned short h0l[64*64];
  __shared__ unsigned short xT[64*64];
  __shared__ unsigned short Gl[64*64];
  __shared__ float dts[64], pl[64], pe[64];
  int c0 = c*CHUNK;
  float Ah = -expf(A_log[h]);
  float Dh = Dp[h];
  // wave0: parallel inclusive prefix scan of lg = dt*A
  if (tid < 64) {
    float dtv = dtb[(size_t)(dir*L_TOK + c0 + tid)*NH + h];
    dts[tid] = dtv;
    float v = dtv*Ah;
    float s = v;
    #pragma unroll
    for (int d = 1; d < 64; d <<= 1) {
      float u = __shfl_up(s, d, 64);
      s += (tid >= d) ? u : 0.f;
    }
    pl[tid] = s;
    pe[tid] = expf(s);
  }
  const unsigned short* Sp = S + ((size_t)(hh*NC + c))*4096;
  #pragma unroll
  for (int i = 0; i < 2; ++i) {
    int q = tid + 256*i;
    int t = q >> 3, d0 = (q & 7)*8;
    int swoff = t*64 + (((q & 7) ^ (t & 7))*8);
    *(short8*)&Cl[swoff] = *(const short8*)(xc + (size_t)(c0+t)*CD + DI + DS + d0);
    *(short8*)&Bl[swoff] = *(const short8*)(xc + (size_t)(c0+t)*CD + DI + d0);
    *(short8*)&h0l[swoff] = *(const short8*)(Sp + (size_t)t*64 + d0);
    short8 xv = *(const short8*)(xc + (size_t)(c0+t)*CD + h*HD + d0);
    int tc = t >> 3, ti = t & 7;
    #pragma unroll
    for (int e = 0; e < 8; ++e) {
      int p = d0 + e;
      xT[p*64 + ((tc ^ (p & 7))*8 + ti)] = (unsigned short)xv[e];
    }
  }
  __syncthreads();
  int t16 = lane & 15, q4 = lane >> 4;
  int t0 = 16*w;
  f32x4 zero = {0.f,0.f,0.f,0.f};
  f32x4 accG[4], accY[4];
  #pragma unroll
  for (int j = 0; j < 4; ++j) { accG[j] = zero; accY[j] = zero; }
  #pragma unroll
  for (int ks = 0; ks < 2; ++ks) {
    int rowA = t0 + t16;
    short8 a = *(const short8*)&Cl[rowA*64 + (((ks*4 + q4) ^ (rowA & 7))*8)];
    #pragma unroll
    for (int j = 0; j < 4; ++j) {
      int rowB = 16*j + t16;
      int off = rowB*64 + (((ks*4 + q4) ^ (rowB & 7))*8);
      accG[j] = __builtin_amdgcn_mfma_f32_16x16x32_bf16(a, *(const short8*)&Bl[off], accG[j], 0, 0, 0);
      accY[j] = __builtin_amdgcn_mfma_f32_16x16x32_bf16(a, *(const short8*)&h0l[off], accY[j], 0, 0, 0);
    }
  }
  #pragma unroll
  for (int j = 0; j < 4; ++j) {
    #pragma unroll
    for (int r = 0; r < 4; ++r) {
      int t = t0 + q4*4 + r;
      int s = 16*j + t16;
      float v = 0.f;
      if (s <= t) {
        v = accG[j][r] * dts[s] * expf(pl[t] - pl[s]);
        if (s == t) v += Dh;
      }
      Gl[t*64 + (((s >> 3) ^ (t & 7))*8 + (s & 7))] = f2bf(v);
    }
  }
  #pragma unroll
  for (int j = 0; j < 4; ++j)
    #pragma unroll
    for (int r = 0; r < 4; ++r)
      accY[j][r] *= pe[t0 + q4*4 + r];
  #pragma unroll
  for (int ks = 0; ks < 2; ++ks) {
    int rowA = t0 + t16;
    short8 a = *(const short8*)&Gl[rowA*64 + (((ks*4 + q4) ^ (rowA & 7))*8)];
    #pragma unroll
    for (int j = 0; j < 4; ++j) {
      int rowB = 16*j + t16;
      short8 b = *(const short8*)&xT[rowB*64 + (((ks*4 + q4) ^ (rowB & 7))*8)];
      accY[j] = __builtin_amdgcn_mfma_f32_16x16x32_bf16(a, b, accY[j], 0, 0, 0);
    }
  }
  #pragma unroll
  for (int j = 0; j < 4; ++j)
    #pragma unroll
    for (int r = 0; r < 4; ++r) {
      int t = t0 + q4*4 + r;
      int p = 16*j + t16;
      y[(size_t)(c0+t)*DI + h*HD + p] = f2bf(accY[j][r]);
    }
}

__global__ void fill_debug(float* out, float v) {
  int i = blockIdx.x*256 + threadIdx.x;
  if (i < L_TOK*DM) out[i] = v;
}

// ---------------- host ----------------

extern "C" void kernel_launch(void* const* d_in, const int* in_sizes, int n_in,
                              void* d_out, int out_size, void* d_ws, size_t ws_size,
                              hipStream_t stream) {
  const float* query = (const float*)d_in[0];
  const float* qpos  = (const float*)d_in[1];
  const float* pre_w = (const float*)d_in[2];
  const float* pre_b = (const float*)d_in[3];
  const float* fin_w = (const float*)d_in[4];
  const float* fin_b = (const float*)d_in[5];
  float* out = (float*)d_out;

  char* ws = (char*)d_ws;
  size_t off = 0;
  auto alloc = [&](size_t bytes) -> void* {
    void* p = ws + off;
    off += (bytes + 255) & ~(size_t)255;
    return p;
  };
  unsigned long long* keys = (unsigned long long*)alloc((size_t)2*L_TOK*8);
  unsigned int* ord = (unsigned int*)alloc((size_t)2*L_TOK*4);
  unsigned int* inv = (unsigned int*)alloc((size_t)2*L_TOK*4);
  unsigned int* rpart = (unsigned int*)alloc((size_t)32*2*L_TOK*4);
  float* pmm  = (float*)alloc(256);
  float* qn   = (float*)alloc((size_t)L_TOK*DM*4);
  unsigned short* qnbf = (unsigned short*)alloc((size_t)L_TOK*DM*2);
  unsigned short* gatebf = (unsigned short*)alloc((size_t)2*L_TOK*DI*2);
  unsigned short* xbcbf  = (unsigned short*)alloc((size_t)2*L_TOK*CD*2);  // also hosts y (stride DI) after conv
  unsigned short* convo  = (unsigned short*)alloc((size_t)2*L_TOK*CD*2);
  float* dtb  = (float*)alloc((size_t)2*L_TOK*NH*4);
  unsigned short* Sbuf = (unsigned short*)alloc((size_t)2*NH*NC*4096*2);
  float* Pbuf = (float*)alloc((size_t)2*NH*NC*4);
  float* Ssum = (float*)alloc((size_t)2*NH*16*4096*4);
  float* Psum = (float*)alloc((size_t)2*NH*16*4);
  unsigned short* WtA = (unsigned short*)alloc((size_t)1152*DM*2);
  unsigned short* WtO = (unsigned short*)alloc((size_t)DM*DI*2);
  if (off > ws_size) {
    fill_debug<<<(L_TOK*DM + 255)/256, 256, 0, stream>>>(out, (float)(ws_size >> 20));
    return;
  }

  minmax_kernel<<<1, 256, 0, stream>>>(qpos, pmm);
  hilbert_kernel<<<L_TOK/256, 256, 0, stream>>>(qpos, pmm, keys);
  rank_partial<<<dim3(16, 2, 32), 256, 0, stream>>>(keys, rpart);
  rank_scatter<<<(2*L_TOK)/256, 256, 0, stream>>>(keys, rpart, ord, inv);

  for (int l = 0; l < 2; ++l) {
    int base = 6 + 8*l;
    const float* in_proj  = (const float*)d_in[base+0];
    const float* conv_w   = (const float*)d_in[base+1];
    const float* conv_b   = (const float*)d_in[base+2];
    const float* dt_bias  = (const float*)d_in[base+3];
    const float* A_log    = (const float*)d_in[base+4];
    const float* Dp       = (const float*)d_in[base+5];
    const float* norm_w   = (const float*)d_in[base+6];
    const float* out_proj = (const float*)d_in[base+7];

    if (l == 0)
      ln_kernel<<<L_TOK/4, 256, 0, stream>>>(query, qn, qnbf, pre_w, pre_b);
    tcvt_both<<<(1152*DM + DM*DI)/256, 256, 0, stream>>>(in_proj, out_proj, WtA, WtO);
    gemm_in_mfma<<<dim3(1152, 1, 2), 256, 0, stream>>>(qnbf, WtA, ord, gatebf, xbcbf);
    dt_gemv<<<(2*L_TOK)/32, 256, 0, stream>>>(qn, in_proj, ord, dt_bias, dtb);
    conv_kernel<<<dim3(10, 128, 2), 256, 0, stream>>>(xbcbf, conv_w, conv_b, convo);
    phaseA_mfma<<<dim3(NC, NH, 2), 256, 0, stream>>>(convo, dtb, A_log, Sbuf, Pbuf);
    phaseB1<<<(16*16*2048)/256, 256, 0, stream>>>(Sbuf, Pbuf, Ssum, Psum);
    phaseB3<<<(16*16*2048)/256, 256, 0, stream>>>(Sbuf, Pbuf, Ssum, Psum);
    phaseC_mfma<<<dim3(NC, NH, 2), 256, 0, stream>>>(convo, dtb, A_log, Dp, Sbuf, xbcbf);
    gating_kernel<<<(2*L_TOK)/4, 256, 0, stream>>>(xbcbf, gatebf, norm_w);
    gemm_out_gather<<<512, 256, 0, stream>>>(xbcbf, WtO, inv,
                                             l ? (const float*)out : query, out);
    if (l == 0)
      lnfuse_kernel<<<L_TOK/4, 256, 0, stream>>>(out, qn, qnbf, fin_w, fin_b, pre_w, pre_b);
    else
      lnfuse_kernel<<<L_TOK/4, 256, 0, stream>>>(out, nullptr, nullptr, fin_w, fin_b, pre_w, pre_b);
  }
}